// Round 12
// baseline (153.300 us; speedup 1.0000x reference)
//
#include <hip/hip_runtime.h>
#include <math.h>

#define KNN  16
#define CZ   128
#define CG   16
#define CS   256
#define NN   1024

typedef __attribute__((ext_vector_type(8))) _Float16 half8;
typedef __attribute__((ext_vector_type(4))) _Float16 half4;
typedef __attribute__((ext_vector_type(2))) _Float16 half2v;
typedef __attribute__((ext_vector_type(4))) float f4_t;

#define MFMA16x32(A, B, C) __builtin_amdgcn_mfma_f32_16x16x32_f16((A), (B), (C), 0, 0, 0)
#define MFMA16x16(A, B, C) __builtin_amdgcn_mfma_f32_16x16x16f16((A), (B), (C), 0, 0, 0)

union U8 { half2v h[4]; half8 v; };
union U4 { half2v h[2]; half4 v; };

__device__ __forceinline__ half2v pk2(float x, float y) {
    auto t = __builtin_amdgcn_cvt_pkrtz(x, y);
    half2v r;
    __builtin_memcpy(&r, &t, 4);
    return r;
}
__device__ __forceinline__ float sig_(float x) {
    return __builtin_amdgcn_rcpf(1.0f + __expf(-x));
}

// ---------------------------------------------------------------------------
// prep kernel: blocks [0,416) repack weights to f16 MFMA frag layouts;
// blocks [416,1440) compute nl/nr (1 node/block, 4 waves split the dot).
// ---------------------------------------------------------------------------
__global__ __launch_bounds__(256) void prep_kernel(
    const float* __restrict__ Wdp, const float* __restrict__ Wdg,
    const float* __restrict__ Wout, const float* __restrict__ Wep,
    const float* __restrict__ Weg, const float* __restrict__ Wog,
    _Float16* __restrict__ pk,
    const float* __restrict__ nf,
    const float* __restrict__ Wl, const float* __restrict__ bl,
    const float* __restrict__ Wr, const float* __restrict__ br,
    float* __restrict__ nlo, float* __restrict__ nro) {
    __shared__ float pl[4][16], pr[4][16];
    int b = blockIdx.x, tid = threadIdx.x;
    if (b < 416) {
        int gid = b * 256 + tid;
        float val;
        if (gid >= 8192 && gid < 40960) {
            int o = gid - 8192;
            int i = o & 3, l = (o >> 2) & 63, ct = (o >> 8) & 7, q = o >> 11;
            int row = (4 * (l >> 4) + i) * 16 + q;
            int col = ct * 16 + (l & 15);
            val = Wdg[row * CZ + col];
        } else {
            const float* srcw;
            int o;
            if (gid < 8192)        { srcw = Wdp;  o = gid; }
            else if (gid < 57344)  { srcw = Wout; o = gid - 40960; }
            else if (gid < 73728)  { srcw = Wep;  o = gid - 57344; }
            else if (gid < 90112)  { srcw = Weg;  o = gid - 73728; }
            else                   { srcw = Wog;  o = gid - 90112; }
            int t = o & 7, l = (o >> 3) & 63, ct = (o >> 9) & 7, s = o >> 12;
            int row = s * 32 + (l >> 4) * 8 + t;
            int col = ct * 16 + (l & 15);
            val = srcw[row * CZ + col];
        }
        pk[gid] = (_Float16)val;
    } else {
        int n = b - 416;
        int wv = tid >> 6, lane = tid & 63;
        int p = lane & 15, sub = lane >> 4;
        int base = wv * 64 + sub * 16;
        const float* rw = nf + n * CS + base;
        const float* wlp = Wl + base * CG + p;
        const float* wrp = Wr + base * CG + p;
        float accl = 0.0f, accr = 0.0f;
        #pragma unroll
        for (int i = 0; i < 16; ++i) {
            float v = rw[i];
            accl += v * wlp[i * CG];
            accr += v * wrp[i * CG];
        }
        accl += __shfl_xor(accl, 16); accl += __shfl_xor(accl, 32);
        accr += __shfl_xor(accr, 16); accr += __shfl_xor(accr, 32);
        if (lane < 16) { pl[wv][lane] = accl; pr[wv][lane] = accr; }
        __syncthreads();
        if (tid < 16) {
            nlo[n * CG + tid] = pl[0][tid] + pl[1][tid] + pl[2][tid] + pl[3][tid] + bl[tid];
        } else if (tid < 32) {
            int p2 = tid - 16;
            nro[n * CG + p2] = pr[0][p2] + pr[1][p2] + pr[2][p2] + pr[3][p2] + br[p2];
        }
    }
}

// ---------------------------------------------------------------------------
// main kernel R12 = R9/R11 structure + latency overlap in the quarter loop:
// wave wv's rbf units (2wv, 2wv+1) belong to j = 4Q+wv, so that j is
// processed from REGISTER frags BEFORE the cross-wave s_fr barrier (all its
// inputs are wave-local: own T, own frags, e2f). The other 3 j's follow the
// barrier in rotated order m=(wv+i)&3 to spread s_fr reads across units.
// ---------------------------------------------------------------------------
__global__ __launch_bounds__(256) void main_kernel(
    const float* __restrict__ trans, const float* __restrict__ ef,
    const float* __restrict__ lng, const float* __restrict__ lnb,
    const float* __restrict__ nl, const float* __restrict__ nr,
    const float* __restrict__ bep, const float* __restrict__ beg,
    const float* __restrict__ bog,
    const _Float16* __restrict__ Wepp, const _Float16* __restrict__ Wegp,
    const _Float16* __restrict__ Wogp,
    const _Float16* __restrict__ Wdg2, const float* __restrict__ bdg,
    const _Float16* __restrict__ Wdpp, const float* __restrict__ bdp,
    const float* __restrict__ lnog, const float* __restrict__ lnob,
    const _Float16* __restrict__ Woutp, const float* __restrict__ bout,
    const int* __restrict__ src, const int* __restrict__ resmask,
    float* __restrict__ out) {
    __shared__ _Float16 s_zu[16 * 136];    // z -> ggf store -> uln
    __shared__ float s_t[64];
    __shared__ float s_km[16];
    __shared__ int   s_src[16];
    __shared__ float s_a[256];             // nl[src[j]][p], stride 16
    __shared__ float s_b[16 * 20];         // nr[src[k]][q], stride 20
    __shared__ _Float16 s_T[4 * 2048];     // per-wave quarter-T (4 KB each)
    __shared__ _Float16 s_fr[8 * 64 * 8];  // rbf frags: 8 units x 64 lanes x 8 f16
    __shared__ _Float16 s_part[16 * CZ * 4]; // quad-partials (j, c, quad)

    int n = blockIdx.x, tid = threadIdx.x;
    if (tid < 16) {
        int sv = src[n * KNN + tid];
        s_src[tid] = sv;
        s_km[tid] = (resmask[sv] != 0 && resmask[n] != 0) ? 1.0f : 0.0f;
        s_t[tid * 4 + 0] = trans[sv * 3 + 0];
        s_t[tid * 4 + 1] = trans[sv * 3 + 1];
        s_t[tid * 4 + 2] = trans[sv * 3 + 2];
    }
    __syncthreads();
    {
        int j = tid >> 4, p = tid & 15;
        int sv = s_src[j];
        s_a[j * 16 + p] = nl[sv * CG + p];
        s_b[j * 20 + p] = nr[sv * CG + p];
    }
    // --- phase 1: LN(ef) -> s_zu ---
    {
        int r = tid >> 4, seg = tid & 15;
        const float* row = ef + ((size_t)n * KNN + r) * CZ + seg * 8;
        f4_t x0 = *(const f4_t*)row;
        f4_t x1 = *(const f4_t*)(row + 4);
        float s = x0.x + x0.y + x0.z + x0.w + x1.x + x1.y + x1.z + x1.w;
        float q = x0.x * x0.x + x0.y * x0.y + x0.z * x0.z + x0.w * x0.w
                + x1.x * x1.x + x1.y * x1.y + x1.z * x1.z + x1.w * x1.w;
        #pragma unroll
        for (int m = 1; m < 16; m <<= 1) { s += __shfl_xor(s, m); q += __shfl_xor(q, m); }
        float mean = s * (1.0f / CZ);
        float var  = q * (1.0f / CZ) - mean * mean;
        float rs   = __builtin_amdgcn_rsqf(var + 1e-5f);
        int col = seg * 8;
        f4_t g0 = *(const f4_t*)(lng + col), g1 = *(const f4_t*)(lng + col + 4);
        f4_t b0 = *(const f4_t*)(lnb + col), b1 = *(const f4_t*)(lnb + col + 4);
        U8 zu;
        zu.h[0] = pk2((x0.x - mean) * rs * g0.x + b0.x, (x0.y - mean) * rs * g0.y + b0.y);
        zu.h[1] = pk2((x0.z - mean) * rs * g0.z + b0.z, (x0.w - mean) * rs * g0.w + b0.w);
        zu.h[2] = pk2((x1.x - mean) * rs * g1.x + b1.x, (x1.y - mean) * rs * g1.y + b1.y);
        zu.h[3] = pk2((x1.z - mean) * rs * g1.z + b1.z, (x1.w - mean) * rs * g1.w + b1.w);
        *(half8*)&s_zu[r * 136 + col] = zu.v;
    }
    __syncthreads();

    int wv = tid >> 6, lane = tid & 63, l15 = lane & 15, quad = lane >> 4;

    // --- phase 2: edge GEMMs -> e2f (km[k] folded), ggf ---
    half8 Az[4];
    #pragma unroll
    for (int st = 0; st < 4; ++st)
        Az[st] = *(const half8*)&s_zu[l15 * 136 + st * 32 + quad * 8];
    f4_t e2f[2], ggf[2];
    #pragma unroll
    for (int cc = 0; cc < 2; ++cc) {
        int ct = wv * 2 + cc;
        int c = ct * 16 + l15;
        float vep = bep[c], veg = beg[c], vog = bog[c];
        f4_t aep = {vep, vep, vep, vep};
        f4_t aeg = {veg, veg, veg, veg};
        f4_t aog = {vog, vog, vog, vog};
        #pragma unroll
        for (int st = 0; st < 4; ++st) {
            int off = ((st * 8 + ct) * 64 + lane) * 8;
            half8 wep_ = *(const half8*)(Wepp + off);
            half8 weg_ = *(const half8*)(Wegp + off);
            half8 wog_ = *(const half8*)(Wogp + off);
            aep = MFMA16x32(Az[st], wep_, aep);
            aeg = MFMA16x32(Az[st], weg_, aeg);
            aog = MFMA16x32(Az[st], wog_, aog);
        }
        #pragma unroll
        for (int rr = 0; rr < 4; ++rr) {
            e2f[cc][rr] = sig_(aeg[rr]) * aep[rr] * s_km[quad * 4 + rr];
            ggf[cc][rr] = sig_(aog[rr]);
        }
    }
    __syncthreads();   // all z-reads done; s_zu becomes ggf parking

    // park ggf (packed f16) in s_zu; frees 8 live VGPRs during j-loop
    {
        U8 g;
        g.h[0] = pk2(ggf[0][0], ggf[0][1]);
        g.h[1] = pk2(ggf[0][2], ggf[0][3]);
        g.h[2] = pk2(ggf[1][0], ggf[1][1]);
        g.h[3] = pk2(ggf[1][2], ggf[1][3]);
        *(half8*)&s_zu[tid * 8] = g.v;
    }

    // persistent Wdp B-frags
    half8 Bdp_[2][2];
    #pragma unroll
    for (int st = 0; st < 2; ++st)
        #pragma unroll
        for (int cc = 0; cc < 2; ++cc)
            Bdp_[st][cc] = *(const half8*)(Wdpp + ((st * 8 + wv * 2 + cc) * 64 + lane) * 8);

    float bdgv[2], bdpv[2];
    #pragma unroll
    for (int cc = 0; cc < 2; ++cc) {
        int c = (wv * 2 + cc) * 16 + l15;
        bdgv[cc] = bdg[c];
        bdpv[cc] = bdp[c];
    }

    // A-frags for T build (Aa = nl rows) and gate (Ab = nr rows)
    half4 Aa, Ab;
    {
        f4_t av = *(const f4_t*)&s_a[l15 * 16 + 4 * quad];
        U4 u; u.h[0] = pk2(av.x, av.y); u.h[1] = pk2(av.z, av.w);
        Aa = u.v;
        f4_t bv = *(const f4_t*)&s_b[l15 * 20 + 4 * quad];
        U4 w; w.h[0] = pk2(bv.x, bv.y); w.h[1] = pk2(bv.z, bv.w);
        Ab = w.v;
    }

    float tkx = s_t[l15 * 4 + 0], tky = s_t[l15 * 4 + 1], tkz = s_t[l15 * 4 + 2];
    const float MUS = 20.0f / 63.0f;
    const float ISG = 1.0f / 0.3125f;
    float rIS[2];
    #pragma unroll
    for (int st = 0; st < 2; ++st)
        rIS[st] = (float)(st * 32 + quad * 8) * (MUS * ISG);

    _Float16* Tw = s_T + wv * 2048;

    for (int Q = 0; Q < 4; ++Q) {
        // --- T build for j in [4Q, 4Q+4): keep rows with quad==Q (m = rr) ---
        #pragma unroll
        for (int ctl = 0; ctl < 2; ++ctl) {
            int ct = wv * 2 + ctl;
            #pragma unroll
            for (int qb = 0; qb < 4; ++qb) {
                f4_t tq[4];
                #pragma unroll
                for (int qq = 0; qq < 4; ++qq) {
                    half4 Bw = *(const half4*)(Wdg2 + (((4 * qb + qq) * 8 + ct) * 64 + lane) * 4);
                    f4_t z = {0.f, 0.f, 0.f, 0.f};
                    tq[qq] = MFMA16x16(Aa, Bw, z);
                }
                if (quad == Q) {
                    #pragma unroll
                    for (int rr = 0; rr < 4; ++rr) {
                        U4 u;
                        u.h[0] = pk2(tq[0][rr], tq[1][rr]);
                        u.h[1] = pk2(tq[2][rr], tq[3][rr]);
                        *(half4*)&Tw[((rr * 2 + ctl) * 64 + l15 + 16 * qb) * 4] = u.v;
                    }
                }
            }
        }

        // --- own rbf frags: units 2wv, 2wv+1 (both belong to j = 4Q+wv) ---
        half8 own[2];
        {
            int j = 4 * Q + wv;
            float dx = s_t[j * 4 + 0] - tkx + 1e-8f;
            float dy = s_t[j * 4 + 1] - tky + 1e-8f;
            float dz = s_t[j * 4 + 2] - tkz + 1e-8f;
            float dI = sqrtf(dx * dx + dy * dy + dz * dz) * ISG;
            #pragma unroll
            for (int st = 0; st < 2; ++st) {
                float base0 = dI - rIS[st];
                U8 cv;
                #pragma unroll
                for (int tt = 0; tt < 4; ++tt) {
                    float u0 = base0 - (float)(2 * tt) * (MUS * ISG);
                    float u1 = u0 - (MUS * ISG);
                    cv.h[tt] = pk2(__expf(-u0 * u0), __expf(-u1 * u1));
                }
                own[st] = cv.v;
                *(half8*)&s_fr[((wv * 2 + st) * 64 + lane) * 8] = cv.v;
            }
        }

        // --- process m == wv BEFORE the barrier (all inputs wave-local) ---
        #pragma unroll
        for (int i = 0; i < 4; ++i) {
            if (i == 1) __syncthreads();   // after own-j; before cross-wave reads
            int m = (wv + i) & 3;
            int j = 4 * Q + m;
            half8 ar0, ar1;
            if (i == 0) { ar0 = own[0]; ar1 = own[1]; }
            else {
                ar0 = *(const half8*)&s_fr[((m * 2 + 0) * 64 + lane) * 8];
                ar1 = *(const half8*)&s_fr[((m * 2 + 1) * 64 + lane) * 8];
            }
            f4_t accd[2], accg[2];
            #pragma unroll
            for (int cc = 0; cc < 2; ++cc) {
                f4_t z = {bdpv[cc], bdpv[cc], bdpv[cc], bdpv[cc]};
                z = MFMA16x32(ar0, Bdp_[0][cc], z);
                z = MFMA16x32(ar1, Bdp_[1][cc], z);
                accd[cc] = z;
                half4 Bt = *(const half4*)&Tw[((m * 2 + cc) * 64 + l15 + 16 * quad) * 4];
                f4_t g = {bdgv[cc], bdgv[cc], bdgv[cc], bdgv[cc]};
                accg[cc] = MFMA16x16(Ab, Bt, g);
            }
            #pragma unroll
            for (int cc = 0; cc < 2; ++cc) {
                float pr = 0.f;
                #pragma unroll
                for (int rr = 0; rr < 4; ++rr)
                    pr += sig_(accg[cc][rr]) * accd[cc][rr] * e2f[cc][rr];
                s_part[(j * CZ + (wv * 2 + cc) * 16 + l15) * 4 + quad] = (_Float16)pr;
            }
        }
        __syncthreads();   // protect s_fr/T for next quarter, s_part for phase 5
    }

    // --- phase 5: retrieve ggf, sum partials + LN, Wout GEMM, gate+mask ---
    half8 gv = *(const half8*)&s_zu[tid * 8];
    __syncthreads();   // all ggf reads done before uln overwrites s_zu

    #pragma unroll
    for (int rr2 = 0; rr2 < 4; ++rr2) {
        int rj = wv * 4 + rr2;
        U4 p0, p1;
        p0.v = *(const half4*)&s_part[(rj * CZ + lane) * 4];
        p1.v = *(const half4*)&s_part[(rj * CZ + lane + 64) * 4];
        half2v t0 = p0.h[0] + p0.h[1];
        half2v t1 = p1.h[0] + p1.h[1];
        float x0 = (float)t0[0] + (float)t0[1];
        float x1 = (float)t1[0] + (float)t1[1];
        float sm = x0 + x1, sq = x0 * x0 + x1 * x1;
        #pragma unroll
        for (int m = 1; m < 64; m <<= 1) {
            sm += __shfl_xor(sm, m);
            sq += __shfl_xor(sq, m);
        }
        float mean = sm * (1.0f / CZ);
        float var  = sq * (1.0f / CZ) - mean * mean;
        float rsv  = __builtin_amdgcn_rsqf(var + 1e-5f);
        float h0 = (x0 - mean) * rsv * lnog[lane] + lnob[lane];
        float h1 = (x1 - mean) * rsv * lnog[64 + lane] + lnob[64 + lane];
        s_zu[rj * 136 + lane]      = (_Float16)h0;
        s_zu[rj * 136 + 64 + lane] = (_Float16)h1;
    }
    __syncthreads();

    half8 Aw[4];
    #pragma unroll
    for (int st = 0; st < 4; ++st)
        Aw[st] = *(const half8*)&s_zu[l15 * 136 + st * 32 + quad * 8];
    #pragma unroll
    for (int cc = 0; cc < 2; ++cc) {
        int ct = wv * 2 + cc;
        int c = ct * 16 + l15;
        float bo = bout[c];
        f4_t acc = {bo, bo, bo, bo};
        #pragma unroll
        for (int st = 0; st < 4; ++st) {
            half8 bw = *(const half8*)(Woutp + ((st * 8 + ct) * 64 + lane) * 8);
            acc = MFMA16x32(Aw[st], bw, acc);
        }
        #pragma unroll
        for (int rr = 0; rr < 4; ++rr) {
            int row = quad * 4 + rr;
            size_t oi = (size_t)(n * KNN + row) * CZ + c;
            out[oi] = acc[rr] * (float)gv[cc * 4 + rr] * s_km[row];
        }
    }
}

extern "C" void kernel_launch(void* const* d_in, const int* in_sizes, int n_in,
                              void* d_out, int out_size, void* d_ws, size_t ws_size,
                              hipStream_t stream) {
    const float* node_features = (const float*)d_in[0];
    const float* trans         = (const float*)d_in[1];
    const float* edge_features = (const float*)d_in[2];
    const float* ln_g  = (const float*)d_in[3];
    const float* ln_b  = (const float*)d_in[4];
    const float* Wl    = (const float*)d_in[5];
    const float* bl    = (const float*)d_in[6];
    const float* Wr    = (const float*)d_in[7];
    const float* br    = (const float*)d_in[8];
    const float* Wep   = (const float*)d_in[9];
    const float* bep   = (const float*)d_in[10];
    const float* Weg   = (const float*)d_in[11];
    const float* beg   = (const float*)d_in[12];
    const float* Wdg   = (const float*)d_in[13];
    const float* bdg   = (const float*)d_in[14];
    const float* Wdp   = (const float*)d_in[15];
    const float* bdp   = (const float*)d_in[16];
    const float* lno_g = (const float*)d_in[17];
    const float* lno_b = (const float*)d_in[18];
    const float* Wout  = (const float*)d_in[19];
    const float* bout  = (const float*)d_in[20];
    const float* Wog   = (const float*)d_in[21];
    const float* bog   = (const float*)d_in[22];
    const int* edge_index = (const int*)d_in[23];
    const int* resmask    = (const int*)d_in[25];

    float* ws = (float*)d_ws;
    float* nl = ws;
    float* nr = nl + NN * CG;
    _Float16* pk = (_Float16*)(nr + NN * CG);
    _Float16* Wdpp  = pk;             // 8192
    _Float16* Wdg2  = pk + 8192;      // 32768
    _Float16* Woutp = pk + 40960;     // 16384
    _Float16* Wepp  = pk + 57344;     // 16384
    _Float16* Wegp  = pk + 73728;     // 16384
    _Float16* Wogp  = pk + 90112;     // 16384
    const int* src = edge_index;      // row 0 of [2, N*K]

    prep_kernel<<<1440, 256, 0, stream>>>(
        Wdp, Wdg, Wout, Wep, Weg, Wog, pk,
        node_features, Wl, bl, Wr, br, nl, nr);
    main_kernel<<<NN, 256, 0, stream>>>(
        trans, edge_features, ln_g, ln_b, nl, nr,
        bep, beg, bog, Wepp, Wegp, Wogp,
        Wdg2, bdg, Wdpp, bdp, lno_g, lno_b,
        Woutp, bout, src, resmask, (float*)d_out);
}

// Round 13
// 148.256 us; speedup vs baseline: 1.0340x; 1.0340x over previous
//
#include <hip/hip_runtime.h>
#include <math.h>

#define KNN  16
#define CZ   128
#define CG   16
#define CS   256
#define NN   1024

typedef __attribute__((ext_vector_type(8))) _Float16 half8;
typedef __attribute__((ext_vector_type(4))) _Float16 half4;
typedef __attribute__((ext_vector_type(2))) _Float16 half2v;
typedef __attribute__((ext_vector_type(4))) float f4_t;

#define MFMA16x32(A, B, C) __builtin_amdgcn_mfma_f32_16x16x32_f16((A), (B), (C), 0, 0, 0)
#define MFMA16x16(A, B, C) __builtin_amdgcn_mfma_f32_16x16x16f16((A), (B), (C), 0, 0, 0)

union U8 { half2v h[4]; half8 v; };
union U4 { half2v h[2]; half4 v; };

__device__ __forceinline__ half2v pk2(float x, float y) {
    auto t = __builtin_amdgcn_cvt_pkrtz(x, y);
    half2v r;
    __builtin_memcpy(&r, &t, 4);
    return r;
}
__device__ __forceinline__ float sig_(float x) {
    return __builtin_amdgcn_rcpf(1.0f + __expf(-x));
}

// ---------------------------------------------------------------------------
// prep kernel: blocks [0,416) repack weights to f16 MFMA frag layouts;
// blocks [416,1440) compute nl/nr (1 node/block, 4 waves split the dot).
// ---------------------------------------------------------------------------
__global__ __launch_bounds__(256) void prep_kernel(
    const float* __restrict__ Wdp, const float* __restrict__ Wdg,
    const float* __restrict__ Wout, const float* __restrict__ Wep,
    const float* __restrict__ Weg, const float* __restrict__ Wog,
    _Float16* __restrict__ pk,
    const float* __restrict__ nf,
    const float* __restrict__ Wl, const float* __restrict__ bl,
    const float* __restrict__ Wr, const float* __restrict__ br,
    float* __restrict__ nlo, float* __restrict__ nro) {
    __shared__ float pl[4][16], pr[4][16];
    int b = blockIdx.x, tid = threadIdx.x;
    if (b < 416) {
        int gid = b * 256 + tid;
        float val;
        if (gid >= 8192 && gid < 40960) {
            int o = gid - 8192;
            int i = o & 3, l = (o >> 2) & 63, ct = (o >> 8) & 7, q = o >> 11;
            int row = (4 * (l >> 4) + i) * 16 + q;
            int col = ct * 16 + (l & 15);
            val = Wdg[row * CZ + col];
        } else {
            const float* srcw;
            int o;
            if (gid < 8192)        { srcw = Wdp;  o = gid; }
            else if (gid < 57344)  { srcw = Wout; o = gid - 40960; }
            else if (gid < 73728)  { srcw = Wep;  o = gid - 57344; }
            else if (gid < 90112)  { srcw = Weg;  o = gid - 73728; }
            else                   { srcw = Wog;  o = gid - 90112; }
            int t = o & 7, l = (o >> 3) & 63, ct = (o >> 9) & 7, s = o >> 12;
            int row = s * 32 + (l >> 4) * 8 + t;
            int col = ct * 16 + (l & 15);
            val = srcw[row * CZ + col];
        }
        pk[gid] = (_Float16)val;
    } else {
        int n = b - 416;
        int wv = tid >> 6, lane = tid & 63;
        int p = lane & 15, sub = lane >> 4;
        int base = wv * 64 + sub * 16;
        const float* rw = nf + n * CS + base;
        const float* wlp = Wl + base * CG + p;
        const float* wrp = Wr + base * CG + p;
        float accl = 0.0f, accr = 0.0f;
        #pragma unroll
        for (int i = 0; i < 16; ++i) {
            float v = rw[i];
            accl += v * wlp[i * CG];
            accr += v * wrp[i * CG];
        }
        accl += __shfl_xor(accl, 16); accl += __shfl_xor(accl, 32);
        accr += __shfl_xor(accr, 16); accr += __shfl_xor(accr, 32);
        if (lane < 16) { pl[wv][lane] = accl; pr[wv][lane] = accr; }
        __syncthreads();
        if (tid < 16) {
            nlo[n * CG + tid] = pl[0][tid] + pl[1][tid] + pl[2][tid] + pl[3][tid] + bl[tid];
        } else if (tid < 32) {
            int p2 = tid - 16;
            nro[n * CG + p2] = pr[0][p2] + pr[1][p2] + pr[2][p2] + pr[3][p2] + br[p2];
        }
    }
}

// ---------------------------------------------------------------------------
// main kernel R13: 512 threads / 8 waves per node; wave wv owns ONE col-tile
// (ct = wv). Halves per-wave register needs and per-j serial chains vs the
// 4-wave version (whose regs >128/wave pinned occupancy at 12 waves/CU).
// Same j-quarter structure: quarter-T (2 KB/wave), cooperative rbf frags
// (1 unit/wave), deferred quad-partial reduction. LDS ~48 KB.
// ---------------------------------------------------------------------------
__global__ __launch_bounds__(512) void main_kernel(
    const float* __restrict__ trans, const float* __restrict__ ef,
    const float* __restrict__ lng, const float* __restrict__ lnb,
    const float* __restrict__ nl, const float* __restrict__ nr,
    const float* __restrict__ bep, const float* __restrict__ beg,
    const float* __restrict__ bog,
    const _Float16* __restrict__ Wepp, const _Float16* __restrict__ Wegp,
    const _Float16* __restrict__ Wogp,
    const _Float16* __restrict__ Wdg2, const float* __restrict__ bdg,
    const _Float16* __restrict__ Wdpp, const float* __restrict__ bdp,
    const float* __restrict__ lnog, const float* __restrict__ lnob,
    const _Float16* __restrict__ Woutp, const float* __restrict__ bout,
    const int* __restrict__ src, const int* __restrict__ resmask,
    float* __restrict__ out) {
    __shared__ _Float16 s_zu[16 * 136];    // z -> ggf park -> uln
    __shared__ float s_t[64];
    __shared__ float s_km[16];
    __shared__ int   s_src[16];
    __shared__ float s_a[256];             // nl[src[j]][p], stride 16
    __shared__ float s_b[16 * 20];         // nr[src[k]][q], stride 20
    __shared__ _Float16 s_T[8 * 1024];     // per-wave quarter-T (2 KB each)
    __shared__ _Float16 s_fr[8 * 64 * 8];  // rbf frags: 8 units x 64 lanes x 8 f16
    __shared__ _Float16 s_part[16 * CZ * 4]; // quad-partials (j, c, quad)

    int n = blockIdx.x, tid = threadIdx.x;
    if (tid < 16) {
        int sv = src[n * KNN + tid];
        s_src[tid] = sv;
        s_km[tid] = (resmask[sv] != 0 && resmask[n] != 0) ? 1.0f : 0.0f;
        s_t[tid * 4 + 0] = trans[sv * 3 + 0];
        s_t[tid * 4 + 1] = trans[sv * 3 + 1];
        s_t[tid * 4 + 2] = trans[sv * 3 + 2];
    }
    __syncthreads();
    if (tid < 256) {
        int j = tid >> 4, p = tid & 15;
        int sv = s_src[j];
        s_a[j * 16 + p] = nl[sv * CG + p];
        s_b[j * 20 + p] = nr[sv * CG + p];
    }
    // --- phase 1: LN(ef) -> s_zu (32 lanes per row, 4 cols each) ---
    {
        int r = tid >> 5, seg = tid & 31;
        int col = seg * 4;
        const float* row = ef + ((size_t)n * KNN + r) * CZ + col;
        f4_t x = *(const f4_t*)row;
        float s = x.x + x.y + x.z + x.w;
        float q = x.x * x.x + x.y * x.y + x.z * x.z + x.w * x.w;
        #pragma unroll
        for (int m = 1; m < 32; m <<= 1) { s += __shfl_xor(s, m); q += __shfl_xor(q, m); }
        float mean = s * (1.0f / CZ);
        float var  = q * (1.0f / CZ) - mean * mean;
        float rs   = __builtin_amdgcn_rsqf(var + 1e-5f);
        f4_t g = *(const f4_t*)(lng + col);
        f4_t bb = *(const f4_t*)(lnb + col);
        U4 zu;
        zu.h[0] = pk2((x.x - mean) * rs * g.x + bb.x, (x.y - mean) * rs * g.y + bb.y);
        zu.h[1] = pk2((x.z - mean) * rs * g.z + bb.z, (x.w - mean) * rs * g.w + bb.w);
        *(half4*)&s_zu[r * 136 + col] = zu.v;
    }
    __syncthreads();

    int wv = tid >> 6, lane = tid & 63, l15 = lane & 15, quad = lane >> 4;
    int ct = wv;               // this wave's col-tile
    int c = ct * 16 + l15;     // this lane's channel

    // --- phase 2: edge GEMMs -> e2f (km[k] folded), ggf ---
    half8 Az[4];
    #pragma unroll
    for (int st = 0; st < 4; ++st)
        Az[st] = *(const half8*)&s_zu[l15 * 136 + st * 32 + quad * 8];
    f4_t e2f, ggf;
    {
        float vep = bep[c], veg = beg[c], vog = bog[c];
        f4_t aep = {vep, vep, vep, vep};
        f4_t aeg = {veg, veg, veg, veg};
        f4_t aog = {vog, vog, vog, vog};
        #pragma unroll
        for (int st = 0; st < 4; ++st) {
            int off = ((st * 8 + ct) * 64 + lane) * 8;
            half8 wep_ = *(const half8*)(Wepp + off);
            half8 weg_ = *(const half8*)(Wegp + off);
            half8 wog_ = *(const half8*)(Wogp + off);
            aep = MFMA16x32(Az[st], wep_, aep);
            aeg = MFMA16x32(Az[st], weg_, aeg);
            aog = MFMA16x32(Az[st], wog_, aog);
        }
        #pragma unroll
        for (int rr = 0; rr < 4; ++rr) {
            e2f[rr] = sig_(aeg[rr]) * aep[rr] * s_km[quad * 4 + rr];
            ggf[rr] = sig_(aog[rr]);
        }
    }
    __syncthreads();   // all z-reads done; s_zu becomes ggf parking

    // park ggf (packed f16): 512 threads x half4 = 2048 halfs (fits 16*136)
    {
        U4 g;
        g.h[0] = pk2(ggf[0], ggf[1]);
        g.h[1] = pk2(ggf[2], ggf[3]);
        *(half4*)&s_zu[tid * 4] = g.v;
    }

    // persistent Wdp B-frags (single ct)
    half8 Bdp_[2];
    #pragma unroll
    for (int st = 0; st < 2; ++st)
        Bdp_[st] = *(const half8*)(Wdpp + ((st * 8 + ct) * 64 + lane) * 8);

    float bdgv = bdg[c], bdpv = bdp[c];

    // A-frags for T build (Aa = nl rows) and gate (Ab = nr rows)
    half4 Aa, Ab;
    {
        f4_t av = *(const f4_t*)&s_a[l15 * 16 + 4 * quad];
        U4 u; u.h[0] = pk2(av.x, av.y); u.h[1] = pk2(av.z, av.w);
        Aa = u.v;
        f4_t bv = *(const f4_t*)&s_b[l15 * 20 + 4 * quad];
        U4 w; w.h[0] = pk2(bv.x, bv.y); w.h[1] = pk2(bv.z, bv.w);
        Ab = w.v;
    }

    float tkx = s_t[l15 * 4 + 0], tky = s_t[l15 * 4 + 1], tkz = s_t[l15 * 4 + 2];
    const float MUS = 20.0f / 63.0f;
    const float ISG = 1.0f / 0.3125f;
    // rbf production: wave wv makes unit u = wv -> j-offset wv>>1, st = wv&1
    int ust = wv & 1;
    float rISu = (float)(ust * 32 + quad * 8) * (MUS * ISG);

    _Float16* Tw = s_T + wv * 1024;

    for (int Q = 0; Q < 4; ++Q) {
        // --- T build for j in [4Q,4Q+4): keep rows quad==Q ---
        #pragma unroll
        for (int qb = 0; qb < 4; ++qb) {
            f4_t tq[4];
            #pragma unroll
            for (int qq = 0; qq < 4; ++qq) {
                half4 Bw = *(const half4*)(Wdg2 + (((4 * qb + qq) * 8 + ct) * 64 + lane) * 4);
                f4_t z = {0.f, 0.f, 0.f, 0.f};
                tq[qq] = MFMA16x16(Aa, Bw, z);
            }
            if (quad == Q) {
                #pragma unroll
                for (int rr = 0; rr < 4; ++rr) {
                    U4 u;
                    u.h[0] = pk2(tq[0][rr], tq[1][rr]);
                    u.h[1] = pk2(tq[2][rr], tq[3][rr]);
                    *(half4*)&Tw[(rr * 64 + l15 + 16 * qb) * 4] = u.v;
                }
            }
        }

        // --- rbf frag: unit u = wv (j = 4Q + (wv>>1), st = wv&1) ---
        {
            int j = 4 * Q + (wv >> 1);
            float dx = s_t[j * 4 + 0] - tkx + 1e-8f;
            float dy = s_t[j * 4 + 1] - tky + 1e-8f;
            float dz = s_t[j * 4 + 2] - tkz + 1e-8f;
            float dI = sqrtf(dx * dx + dy * dy + dz * dz) * ISG;
            float base0 = dI - rISu;
            U8 cv;
            #pragma unroll
            for (int tt = 0; tt < 4; ++tt) {
                float u0 = base0 - (float)(2 * tt) * (MUS * ISG);
                float u1 = u0 - (MUS * ISG);
                cv.h[tt] = pk2(__expf(-u0 * u0), __expf(-u1 * u1));
            }
            *(half8*)&s_fr[(wv * 64 + lane) * 8] = cv.v;
        }
        __syncthreads();

        // --- j-loop over quarter ---
        for (int m = 0; m < 4; ++m) {
            int j = 4 * Q + m;
            half8 ar0 = *(const half8*)&s_fr[((m * 2 + 0) * 64 + lane) * 8];
            half8 ar1 = *(const half8*)&s_fr[((m * 2 + 1) * 64 + lane) * 8];
            f4_t accd = {bdpv, bdpv, bdpv, bdpv};
            accd = MFMA16x32(ar0, Bdp_[0], accd);
            accd = MFMA16x32(ar1, Bdp_[1], accd);
            half4 Bt = *(const half4*)&Tw[(m * 64 + l15 + 16 * quad) * 4];
            f4_t accg = {bdgv, bdgv, bdgv, bdgv};
            accg = MFMA16x16(Ab, Bt, accg);
            float pr = 0.f;
            #pragma unroll
            for (int rr = 0; rr < 4; ++rr)
                pr += sig_(accg[rr]) * accd[rr] * e2f[rr];
            s_part[(j * CZ + c) * 4 + quad] = (_Float16)pr;
        }
        __syncthreads();   // protect s_fr/T for next quarter, s_part for phase 5
    }

    // --- phase 5: retrieve ggf, sum partials + LN, Wout GEMM, gate+mask ---
    half4 gv = *(const half4*)&s_zu[tid * 4];
    __syncthreads();   // ggf reads done before uln overwrites s_zu

    #pragma unroll
    for (int rr2 = 0; rr2 < 2; ++rr2) {
        int rj = wv * 2 + rr2;
        U4 p0, p1;
        p0.v = *(const half4*)&s_part[(rj * CZ + lane) * 4];
        p1.v = *(const half4*)&s_part[(rj * CZ + lane + 64) * 4];
        half2v t0 = p0.h[0] + p0.h[1];
        half2v t1 = p1.h[0] + p1.h[1];
        float x0 = (float)t0[0] + (float)t0[1];
        float x1 = (float)t1[0] + (float)t1[1];
        float sm = x0 + x1, sq = x0 * x0 + x1 * x1;
        #pragma unroll
        for (int m = 1; m < 64; m <<= 1) {
            sm += __shfl_xor(sm, m);
            sq += __shfl_xor(sq, m);
        }
        float mean = sm * (1.0f / CZ);
        float var  = sq * (1.0f / CZ) - mean * mean;
        float rsv  = __builtin_amdgcn_rsqf(var + 1e-5f);
        float h0 = (x0 - mean) * rsv * lnog[lane] + lnob[lane];
        float h1 = (x1 - mean) * rsv * lnog[64 + lane] + lnob[64 + lane];
        s_zu[rj * 136 + lane]      = (_Float16)h0;
        s_zu[rj * 136 + 64 + lane] = (_Float16)h1;
    }
    __syncthreads();

    half8 Aw[4];
    #pragma unroll
    for (int st = 0; st < 4; ++st)
        Aw[st] = *(const half8*)&s_zu[l15 * 136 + st * 32 + quad * 8];
    {
        float bo = bout[c];
        f4_t acc = {bo, bo, bo, bo};
        #pragma unroll
        for (int st = 0; st < 4; ++st) {
            half8 bw = *(const half8*)(Woutp + ((st * 8 + ct) * 64 + lane) * 8);
            acc = MFMA16x32(Aw[st], bw, acc);
        }
        #pragma unroll
        for (int rr = 0; rr < 4; ++rr) {
            int row = quad * 4 + rr;
            size_t oi = (size_t)(n * KNN + row) * CZ + c;
            out[oi] = acc[rr] * (float)gv[rr] * s_km[row];
        }
    }
}

extern "C" void kernel_launch(void* const* d_in, const int* in_sizes, int n_in,
                              void* d_out, int out_size, void* d_ws, size_t ws_size,
                              hipStream_t stream) {
    const float* node_features = (const float*)d_in[0];
    const float* trans         = (const float*)d_in[1];
    const float* edge_features = (const float*)d_in[2];
    const float* ln_g  = (const float*)d_in[3];
    const float* ln_b  = (const float*)d_in[4];
    const float* Wl    = (const float*)d_in[5];
    const float* bl    = (const float*)d_in[6];
    const float* Wr    = (const float*)d_in[7];
    const float* br    = (const float*)d_in[8];
    const float* Wep   = (const float*)d_in[9];
    const float* bep   = (const float*)d_in[10];
    const float* Weg   = (const float*)d_in[11];
    const float* beg   = (const float*)d_in[12];
    const float* Wdg   = (const float*)d_in[13];
    const float* bdg   = (const float*)d_in[14];
    const float* Wdp   = (const float*)d_in[15];
    const float* bdp   = (const float*)d_in[16];
    const float* lno_g = (const float*)d_in[17];
    const float* lno_b = (const float*)d_in[18];
    const float* Wout  = (const float*)d_in[19];
    const float* bout  = (const float*)d_in[20];
    const float* Wog   = (const float*)d_in[21];
    const float* bog   = (const float*)d_in[22];
    const int* edge_index = (const int*)d_in[23];
    const int* resmask    = (const int*)d_in[25];

    float* ws = (float*)d_ws;
    float* nl = ws;
    float* nr = nl + NN * CG;
    _Float16* pk = (_Float16*)(nr + NN * CG);
    _Float16* Wdpp  = pk;             // 8192
    _Float16* Wdg2  = pk + 8192;      // 32768
    _Float16* Woutp = pk + 40960;     // 16384
    _Float16* Wepp  = pk + 57344;     // 16384
    _Float16* Wegp  = pk + 73728;     // 16384
    _Float16* Wogp  = pk + 90112;     // 16384
    const int* src = edge_index;      // row 0 of [2, N*K]

    prep_kernel<<<1440, 256, 0, stream>>>(
        Wdp, Wdg, Wout, Wep, Weg, Wog, pk,
        node_features, Wl, bl, Wr, br, nl, nr);
    main_kernel<<<NN, 512, 0, stream>>>(
        trans, edge_features, ln_g, ln_b, nl, nr,
        bep, beg, bog, Wepp, Wegp, Wogp,
        Wdg2, bdg, Wdpp, bdp, lno_g, lno_b,
        Woutp, bout, src, resmask, (float*)d_out);
}